// Round 9
// baseline (158.054 us; speedup 1.0000x reference)
//
#include <hip/hip_runtime.h>
#include <hip/hip_bf16.h>
#include <hip/hip_fp16.h>

#define N_B 16
#define C_DIM 256
#define HW 4096
#define M_TOT (N_B*HW)          // 65536 global rows
#define K_A 512
#define TEMP_INV (1.0f/0.3f)
#define EPS_SK 1e-12f

typedef _Float16 f16x8 __attribute__((ext_vector_type(8)));
typedef _Float16 f16x4 __attribute__((ext_vector_type(4)));
typedef float f32x4 __attribute__((ext_vector_type(4)));

#define GLOBAL_AS __attribute__((address_space(1)))
#define LDS_AS __attribute__((address_space(3)))
__device__ __forceinline__ void gload_lds16(const void* g, void* l){
    __builtin_amdgcn_global_load_lds((GLOBAL_AS const void*)g, (LDS_AS void*)l, 16, 0, 0);
}

// ---------------- fused: read x once -> L2 norm -> Lt[n][hw][c] fp16; init u=1,v=1,barrier=0 ----------------
__global__ __launch_bounds__(256) void k_normtrans(const float* __restrict__ x,
                                                   _Float16* __restrict__ Lt,
                                                   float* __restrict__ u,
                                                   float* __restrict__ v,
                                                   unsigned* bcnt, unsigned* bgen){
    __shared__ float tl[32][257];
    __shared__ float red[8][32];
    __shared__ float invs[32];
    int n   = blockIdx.x >> 7;           // 2048 blocks: 16 n x 128 hw-chunks of 32
    int hw0 = (blockIdx.x & 127) * 32;
    if (threadIdx.x < 32) u[blockIdx.x*32 + threadIdx.x] = 1.0f;
    if (blockIdx.x < 2)   v[blockIdx.x*256 + threadIdx.x] = 1.0f;
    if (blockIdx.x == 0 && threadIdx.x == 0){
        __hip_atomic_store(bcnt, 0u, __ATOMIC_RELAXED, __HIP_MEMORY_SCOPE_AGENT);
        __hip_atomic_store(bgen, 0u, __ATOMIC_RELAXED, __HIP_MEMORY_SCOPE_AGENT);
    }
    int tx4 = threadIdx.x & 7;           // hw quad
    int cy  = threadIdx.x >> 3;          // 0..31
    const float* px = x + ((size_t)(n*C_DIM + cy))*HW + hw0 + tx4*4;
    #pragma unroll
    for (int r = 0; r < 8; ++r){
        float4 xv = *(const float4*)(px + (size_t)(r*32)*HW);
        int c = cy + r*32;
        tl[tx4*4+0][c] = xv.x;
        tl[tx4*4+1][c] = xv.y;
        tl[tx4*4+2][c] = xv.z;
        tl[tx4*4+3][c] = xv.w;
    }
    __syncthreads();
    int tx = threadIdx.x & 31, ty = threadIdx.x >> 5;   // ty 0..7
    float ss = 0.f;
    #pragma unroll
    for (int cc = 0; cc < 32; ++cc){
        float tv = tl[tx][cc*8 + ty];
        ss += tv*tv;
    }
    red[ty][tx] = ss;
    __syncthreads();
    if (ty == 0){
        float s = red[0][tx]+red[1][tx]+red[2][tx]+red[3][tx]
                + red[4][tx]+red[5][tx]+red[6][tx]+red[7][tx];
        invs[tx] = 1.0f / fmaxf(sqrtf(s), 1e-12f);
    }
    __syncthreads();
    #pragma unroll
    for (int r = 0; r < 4; ++r){
        int hwl = ty + r*8;
        float inv = invs[hwl];
        f16x8 h;
        #pragma unroll
        for (int e = 0; e < 8; ++e) h[e] = (_Float16)(tl[hwl][tx*8 + e] * inv);
        *(f16x8*)&Lt[((size_t)(n*HW + hw0 + hwl))*C_DIM + tx*8] = h;
    }
}

// ---------------- gather anchors from Lt (coalesced): sxT[n][j][c] fp16 ----------------
__global__ __launch_bounds__(256) void k_gather(const _Float16* __restrict__ Lt,
                                                const int* __restrict__ sidx,
                                                _Float16* __restrict__ sxT){
    int n  = blockIdx.y;
    int jj = blockIdx.x*8 + (threadIdx.x >> 5);
    int c8 = (threadIdx.x & 31) * 8;
    int p  = sidx[jj];
    *(f16x8*)&sxT[((size_t)(n*K_A + jj))*C_DIM + c8] =
        *(const f16x8*)&Lt[((size_t)(n*HW + p))*C_DIM + c8];
}

// ======== GEMM1 + first Sinkhorn column partials ========
__global__ __launch_bounds__(256) void k_gemm1(const _Float16* __restrict__ Lt,
                                               const _Float16* __restrict__ sxT,
                                               _Float16* __restrict__ A0,
                                               float* __restrict__ part){
    __shared__ _Float16 As[3*128*32];
    __shared__ _Float16 Bs[3*128*32];
    __shared__ float colred[4][128];
    const int swz = (blockIdx.x & 7)*256 + (blockIdx.x >> 3);
    const int jb = swz & 3, mb = (swz >> 2) & 31, nb = swz >> 7;
    const int mbase = mb * 128;
    const int jbase = jb * 128;
    const int t = threadIdx.x;
    const int lane = t & 63, w = t >> 6;
    const int wm = (w >> 1)*64, wn = (w & 1)*64;
    const int l15 = lane & 15, lq = lane >> 4;

    f32x4 acc[4][4] = {};
    const _Float16* pa = Lt  + ((size_t)(nb*HW  + mbase))*C_DIM;
    const _Float16* pb = sxT + ((size_t)(nb*K_A + jbase))*C_DIM;

    const int r0 = t >> 2, ch = t & 3;
    const int r1 = r0 + 64;
    const int cs0 = (ch ^ ((r0 >> 1) & 3)) << 3;
    const int cs1 = (ch ^ ((r1 >> 1) & 3)) << 3;

#define STAGE1(buf, kt) { int k0 = (kt)*32; \
    gload_lds16(pa + (size_t)r0*C_DIM + k0 + cs0, &As[(buf)*4096 + t*8]); \
    gload_lds16(pa + (size_t)r1*C_DIM + k0 + cs1, &As[(buf)*4096 + (256+t)*8]); \
    gload_lds16(pb + (size_t)r0*C_DIM + k0 + cs0, &Bs[(buf)*4096 + t*8]); \
    gload_lds16(pb + (size_t)r1*C_DIM + k0 + cs1, &Bs[(buf)*4096 + (256+t)*8]); }

    STAGE1(0, 0); STAGE1(1, 1); STAGE1(2, 2);
    #pragma unroll
    for (int kt = 0; kt < 8; ++kt){
        if (kt < 6)      asm volatile("s_waitcnt vmcnt(8)" ::: "memory");
        else if (kt < 7) asm volatile("s_waitcnt vmcnt(4)" ::: "memory");
        else             asm volatile("s_waitcnt vmcnt(0)" ::: "memory");
        __builtin_amdgcn_s_barrier();
        __builtin_amdgcn_sched_barrier(0);
        const int cur = kt % 3;
        f16x8 af[4], bf[4];
        #pragma unroll
        for (int mi = 0; mi < 4; ++mi){
            int r = wm + mi*16 + l15;
            af[mi] = *(const f16x8*)&As[cur*4096 + r*32 + ((lq ^ ((r>>1)&3)) << 3)];
        }
        #pragma unroll
        for (int ni = 0; ni < 4; ++ni){
            int r = wn + ni*16 + l15;
            bf[ni] = *(const f16x8*)&Bs[cur*4096 + r*32 + ((lq ^ ((r>>1)&3)) << 3)];
        }
        #pragma unroll
        for (int mi = 0; mi < 4; ++mi)
            #pragma unroll
            for (int ni = 0; ni < 4; ++ni)
                acc[mi][ni] = __builtin_amdgcn_mfma_f32_16x16x32_f16(af[mi], bf[ni], acc[mi][ni], 0, 0, 0);
        __builtin_amdgcn_s_barrier();
        __builtin_amdgcn_sched_barrier(0);
        if (kt < 5) STAGE1((kt+3)%3, kt+3);
    }
    float csum[4] = {0.f, 0.f, 0.f, 0.f};
    #pragma unroll
    for (int mi = 0; mi < 4; ++mi)
        #pragma unroll
        for (int ni = 0; ni < 4; ++ni)
            #pragma unroll
            for (int r = 0; r < 4; ++r){
                int hw = mbase + wm + mi*16 + lq*4 + r;
                int j  = jbase + wn + ni*16 + l15;
                float e = __expf(acc[mi][ni][r] * TEMP_INV);
                A0[((size_t)(nb*HW + hw))*K_A + j] = (_Float16)e;
                csum[ni] += e;
            }
    #pragma unroll
    for (int ni = 0; ni < 4; ++ni){
        float cv = csum[ni];
        cv += __shfl_xor(cv, 16);
        cv += __shfl_xor(cv, 32);
        if (lane < 16) colred[w][wn + ni*16 + l15] = cv;
    }
    __syncthreads();
    if (t < 128){
        int jj = t;
        float s = (jj < 64) ? (colred[0][jj] + colred[2][jj])
                            : (colred[1][jj] + colred[3][jj]);
        part[((size_t)(nb*32 + mb))*K_A + jbase + jj] = s;
    }
}

// v[j] <- 128 * v[j] / max(v[j]*S_j, EPS)  (fallback path)
__global__ __launch_bounds__(64) void k_colfinish(const float* __restrict__ part,
                                                  float* __restrict__ v, int nchunks){
    int j = blockIdx.x;
    int lane = threadIdx.x;
    float s = 0.f;
    for (int r = lane; r < nchunks; r += 64) s += part[(size_t)r*K_A + j];
    #pragma unroll
    for (int off = 32; off; off >>= 1) s += __shfl_xor(s, off);
    if (lane == 0){
        float vo = v[j];
        v[j] = 128.0f * vo / fmaxf(vo * s, EPS_SK);
    }
}

// ---------------- FUSED row+col pass (fallback path) ----------------
__global__ __launch_bounds__(256) void k_fused(const _Float16* __restrict__ A0,
                                               const float* __restrict__ v,
                                               float* __restrict__ u,
                                               float* __restrict__ part){
    __shared__ float red[4][512];
    int b = blockIdx.x;
    int tg = threadIdx.x >> 6, lane = threadIdx.x & 63;
    float vr[8];
    const float* pv = v + (lane << 3);
    #pragma unroll
    for (int e = 0; e < 8; ++e) vr[e] = pv[e];
    float acc[8] = {};
    for (int it = 0; it < 16; ++it){
        int i = (b << 6) + (it << 2) + tg;
        f16x8 a = *(const f16x8*)&A0[(size_t)i*K_A + (lane << 3)];
        float r = 0.f;
        #pragma unroll
        for (int e = 0; e < 8; ++e) r += (float)a[e] * vr[e];
        #pragma unroll
        for (int off = 32; off; off >>= 1) r += __shfl_xor(r, off);
        float uo = u[i];
        float un = uo / fmaxf(uo * r, EPS_SK);
        if (lane == 0) u[i] = un;
        #pragma unroll
        for (int e = 0; e < 8; ++e) acc[e] += (float)a[e] * un;
    }
    #pragma unroll
    for (int e = 0; e < 8; ++e) red[tg][(lane<<3)+e] = acc[e];
    __syncthreads();
    if (tg == 0){
        #pragma unroll
        for (int e = 0; e < 8; ++e){
            int j = (lane<<3)+e;
            part[((size_t)b)*K_A + j] = red[0][j]+red[1][j]+red[2][j]+red[3][j];
        }
    }
}

// ---------------- custom sense-reversing grid barrier (512 blocks) ----------------
__device__ __forceinline__ void gbar(unsigned* cnt, unsigned* gen){
    __threadfence();
    __syncthreads();
    if (threadIdx.x == 0){
        unsigned g = __hip_atomic_load(gen, __ATOMIC_RELAXED, __HIP_MEMORY_SCOPE_AGENT);
        unsigned a = __hip_atomic_fetch_add(cnt, 1u, __ATOMIC_ACQ_REL, __HIP_MEMORY_SCOPE_AGENT);
        if (a == 511u){
            __hip_atomic_store(cnt, 0u, __ATOMIC_RELAXED, __HIP_MEMORY_SCOPE_AGENT);
            __hip_atomic_store(gen, g + 1u, __ATOMIC_RELEASE, __HIP_MEMORY_SCOPE_AGENT);
        } else {
            while (__hip_atomic_load(gen, __ATOMIC_ACQUIRE, __HIP_MEMORY_SCOPE_AGENT) == g)
                __builtin_amdgcn_s_sleep(8);
        }
    }
    __syncthreads();
    __threadfence();
}

// col-normalize finish inside k_sink: block b owns column j=b
__device__ __forceinline__ void colfin(const float* part, float* v, int b, int t){
    if (t < 64){
        float s = 0.f;
        #pragma unroll
        for (int g = 0; g < 8; ++g)
            s += __hip_atomic_load(&part[(size_t)(t + g*64)*K_A + b],
                                   __ATOMIC_RELAXED, __HIP_MEMORY_SCOPE_AGENT);
        #pragma unroll
        for (int off = 32; off; off >>= 1) s += __shfl_xor(s, off);
        if (t == 0){
            float vo = __hip_atomic_load(&v[b], __ATOMIC_RELAXED, __HIP_MEMORY_SCOPE_AGENT);
            __hip_atomic_store(&v[b], 128.0f * vo / fmaxf(vo * s, EPS_SK),
                               __ATOMIC_RELAXED, __HIP_MEMORY_SCOPE_AGENT);
        }
    }
}

// ======== Cooperative in-register Sinkhorn: A0 read ONCE; 6 custom grid barriers ========
__global__ __launch_bounds__(512, 4) void k_sink(const _Float16* __restrict__ A0,
                                                 float* v, float* u, float* part,
                                                 unsigned* bcnt, unsigned* bgen){
    __shared__ float red[8][512];
    const int b = blockIdx.x, t = threadIdx.x;
    const int tg = t >> 6, lane = t & 63;
    const int i0 = (b << 7) + tg;
    f16x8 a[16];
    float ur[16];
    #pragma unroll
    for (int it = 0; it < 16; ++it){
        a[it] = *(const f16x8*)&A0[(size_t)(i0 + it*8)*K_A + (lane<<3)];
        ur[it] = 1.0f;
    }
    colfin(part, v, b, t);           // v1 from gemm1 partials (u0 = 1)
    gbar(bcnt, bgen);
    float vr[8];
    #pragma unroll
    for (int e = 0; e < 8; ++e)
        vr[e] = __hip_atomic_load(&v[(lane<<3)+e], __ATOMIC_RELAXED, __HIP_MEMORY_SCOPE_AGENT);
    for (int t3 = 0; t3 < 3; ++t3){
        if (t3){
            gbar(bcnt, bgen);
            #pragma unroll
            for (int e = 0; e < 8; ++e)
                vr[e] = __hip_atomic_load(&v[(lane<<3)+e], __ATOMIC_RELAXED, __HIP_MEMORY_SCOPE_AGENT);
        }
        // row update: ur <- ur / max(ur * (a . v), EPS)  (r wave-uniform after shfl)
        #pragma unroll
        for (int it = 0; it < 16; ++it){
            float r = 0.f;
            #pragma unroll
            for (int e = 0; e < 8; ++e) r += (float)a[it][e] * vr[e];
            #pragma unroll
            for (int off = 32; off; off >>= 1) r += __shfl_xor(r, off);
            ur[it] = ur[it] / fmaxf(ur[it] * r, EPS_SK);
        }
        // column partials over this block's 128 rows
        float acc[8] = {0.f,0.f,0.f,0.f,0.f,0.f,0.f,0.f};
        #pragma unroll
        for (int it = 0; it < 16; ++it)
            #pragma unroll
            for (int e = 0; e < 8; ++e) acc[e] += (float)a[it][e] * ur[it];
        #pragma unroll
        for (int e = 0; e < 8; ++e) red[tg][(lane<<3)+e] = acc[e];
        __syncthreads();
        {
            float s = red[0][t]+red[1][t]+red[2][t]+red[3][t]
                    + red[4][t]+red[5][t]+red[6][t]+red[7][t];
            __hip_atomic_store(&part[(size_t)b*K_A + t], s,
                               __ATOMIC_RELAXED, __HIP_MEMORY_SCOPE_AGENT);
        }
        gbar(bcnt, bgen);
        colfin(part, v, b, t);       // v_{t3+2}
    }
    if (lane == 0){
        #pragma unroll
        for (int it = 0; it < 16; ++it) u[i0 + it*8] = ur[it];   // u3
    }
}

// ---------------- SXv[n][c][j] = sxT[n][j][c] * v[j]  (LDS transpose, fp16) ----------------
__global__ __launch_bounds__(256) void k_sxvT(const _Float16* __restrict__ sxT,
                                              const float* __restrict__ v,
                                              _Float16* __restrict__ SXv){
    __shared__ float tl[64][65];
    int n  = blockIdx.z;
    int j0 = blockIdx.x * 64;
    int c0 = blockIdx.y * 64;
    int tx = threadIdx.x & 63, ty = threadIdx.x >> 6;
    #pragma unroll
    for (int r = 0; r < 16; ++r){
        int jl = ty + r*4;
        tl[jl][tx] = (float)sxT[((size_t)(n*K_A + j0 + jl))*C_DIM + c0 + tx] * v[j0 + jl];
    }
    __syncthreads();
    #pragma unroll
    for (int r = 0; r < 16; ++r){
        int cl = ty + r*4;
        SXv[((size_t)(n*C_DIM + c0 + cl))*K_A + j0 + tx] = (_Float16)tl[tx][cl];
    }
}

// ======== GEMM2 + final row-normalize ========
__global__ __launch_bounds__(256) void k_gemm2(const _Float16* __restrict__ SXv,
                                               const _Float16* __restrict__ A0,
                                               const float* __restrict__ v,
                                               const float* __restrict__ u,
                                               float* __restrict__ out){
    __shared__ _Float16 As[3*128*32];
    __shared__ _Float16 Bs[3*128*32];
    __shared__ _Float16 vsh[512];
    const int swz = (blockIdx.x & 7)*128 + (blockIdx.x >> 3);
    const int mb = swz & 1, nbi = (swz >> 1) & 31, nb = swz >> 6;
    const int mbase = mb * 128;    // c
    const int nbase = nbi * 128;   // hw
    const int t = threadIdx.x;
    const int lane = t & 63, w = t >> 6;
    const int wm = (w >> 1)*64, wn = (w & 1)*64;
    const int l15 = lane & 15, lq = lane >> 4;

    vsh[t]       = (_Float16)v[t];
    vsh[t + 256] = (_Float16)v[t + 256];

    f32x4 acc[4][4] = {};
    f32x4 racc[4] = {};
    const _Float16* pa = SXv + ((size_t)(nb*C_DIM + mbase))*K_A;
    const _Float16* pb = A0  + ((size_t)(nb*HW   + nbase))*K_A;

    const int r0 = t >> 2, ch = t & 3;
    const int r1 = r0 + 64;
    const int cs0 = (ch ^ ((r0 >> 1) & 3)) << 3;
    const int cs1 = (ch ^ ((r1 >> 1) & 3)) << 3;

#define STAGE2(buf, kt) { int k0 = (kt)*32; \
    gload_lds16(pa + (size_t)r0*K_A + k0 + cs0, &As[(buf)*4096 + t*8]); \
    gload_lds16(pa + (size_t)r1*K_A + k0 + cs1, &As[(buf)*4096 + (256+t)*8]); \
    gload_lds16(pb + (size_t)r0*K_A + k0 + cs0, &Bs[(buf)*4096 + t*8]); \
    gload_lds16(pb + (size_t)r1*K_A + k0 + cs1, &Bs[(buf)*4096 + (256+t)*8]); }

    STAGE2(0, 0); STAGE2(1, 1); STAGE2(2, 2);
    #pragma unroll
    for (int kt = 0; kt < 16; ++kt){
        if (kt < 14)      asm volatile("s_waitcnt vmcnt(8)" ::: "memory");
        else if (kt < 15) asm volatile("s_waitcnt vmcnt(4)" ::: "memory");
        else              asm volatile("s_waitcnt vmcnt(0)" ::: "memory");
        __builtin_amdgcn_s_barrier();
        __builtin_amdgcn_sched_barrier(0);
        const int cur = kt % 3;
        f16x8 af[4], bf[4], vf;
        vf = *(const f16x8*)&vsh[kt*32 + lq*8];
        #pragma unroll
        for (int mi = 0; mi < 4; ++mi){
            int r = wm + mi*16 + l15;
            af[mi] = *(const f16x8*)&As[cur*4096 + r*32 + ((lq ^ ((r>>1)&3)) << 3)];
        }
        #pragma unroll
        for (int ni = 0; ni < 4; ++ni){
            int r = wn + ni*16 + l15;
            bf[ni] = *(const f16x8*)&Bs[cur*4096 + r*32 + ((lq ^ ((r>>1)&3)) << 3)];
        }
        #pragma unroll
        for (int mi = 0; mi < 4; ++mi)
            #pragma unroll
            for (int ni = 0; ni < 4; ++ni)
                acc[mi][ni] = __builtin_amdgcn_mfma_f32_16x16x32_f16(af[mi], bf[ni], acc[mi][ni], 0, 0, 0);
        #pragma unroll
        for (int ni = 0; ni < 4; ++ni)
            racc[ni] = __builtin_amdgcn_mfma_f32_16x16x32_f16(vf, bf[ni], racc[ni], 0, 0, 0);
        __builtin_amdgcn_s_barrier();
        __builtin_amdgcn_sched_barrier(0);
        if (kt < 13) STAGE2((kt+3)%3, kt+3);
    }
    float un[4];
    #pragma unroll
    for (int ni = 0; ni < 4; ++ni){
        float rv = racc[ni][0];
        float uo = u[nb*HW + nbase + wn + ni*16 + l15];
        un[ni] = uo / fmaxf(uo * rv, EPS_SK);
    }
    #pragma unroll
    for (int mi = 0; mi < 4; ++mi)
        #pragma unroll
        for (int ni = 0; ni < 4; ++ni)
            #pragma unroll
            for (int r = 0; r < 4; ++r){
                int c  = mbase + wm + mi*16 + lq*4 + r;
                int hw = nbase + wn + ni*16 + l15;
                out[((size_t)(nb*C_DIM + c))*HW + hw] = acc[mi][ni][r] * un[ni];
            }
}

extern "C" void kernel_launch(void* const* d_in, const int* in_sizes, int n_in,
                              void* d_out, int out_size, void* d_ws, size_t ws_size,
                              hipStream_t stream){
    const float* x  = (const float*)d_in[0];
    const int* sidx = (const int*)d_in[1];
    float* out = (float*)d_out;

    char* ws = (char*)d_ws;
    _Float16* Lt  = (_Float16*)ws;  ws += (size_t)N_B*HW*C_DIM*2;      // 32 MiB
    _Float16* A0  = (_Float16*)ws;  ws += (size_t)M_TOT*K_A*2;         // 64 MiB
    _Float16* sxT = (_Float16*)ws;  ws += (size_t)N_B*K_A*C_DIM*2;     // 4 MiB
    _Float16* SXv = (_Float16*)ws;  ws += (size_t)N_B*C_DIM*K_A*2;     // 4 MiB
    float*    u   = (float*)ws;     ws += (size_t)M_TOT*4;
    float*    v   = (float*)ws;     ws += (size_t)K_A*4;
    float*    part= (float*)ws;     ws += (size_t)1024*K_A*4;          // 2 MiB
    unsigned* bcnt= (unsigned*)ws;  ws += 256;
    unsigned* bgen= (unsigned*)ws;  ws += 256;

    k_normtrans<<<2048, 256, 0, stream>>>(x, Lt, u, v, bcnt, bgen);
    k_gather   <<<dim3(64,16), 256, 0, stream>>>(Lt, sidx, sxT);
    k_gemm1    <<<2048, 256, 0, stream>>>(Lt, sxT, A0, part);

    // Sinkhorn middle: cooperative register-resident path if it fits, else round-7 fallback.
    int occ = 0;
    hipError_t oe = hipOccupancyMaxActiveBlocksPerMultiprocessor(&occ, k_sink, 512, 0);
    bool coop = (oe == hipSuccess) && (occ >= 2);
    if (coop){
        void* kargs[] = { (void*)&A0, (void*)&v, (void*)&u, (void*)&part,
                          (void*)&bcnt, (void*)&bgen };
        coop = (hipLaunchCooperativeKernel((void*)k_sink, dim3(512), dim3(512),
                                           kargs, 0, stream) == hipSuccess);
    }
    if (!coop){
        k_colfinish<<<512, 64, 0, stream>>>(part, v, 512);
        for (int it = 0; it < 3; ++it){
            k_fused    <<<1024, 256, 0, stream>>>(A0, v, u, part);
            k_colfinish<<<512, 64, 0, stream>>>(part, v, 1024);
        }
    }

    k_sxvT <<<dim3(8,4,16), 256, 0, stream>>>(sxT, v, SXv);
    k_gemm2<<<1024, 256, 0, stream>>>(SXv, A0, v, u, out);
}

// Round 10
// 156.787 us; speedup vs baseline: 1.0081x; 1.0081x over previous
//
#include <hip/hip_runtime.h>
#include <hip/hip_bf16.h>
#include <hip/hip_fp16.h>

#define N_B 16
#define C_DIM 256
#define HW 4096
#define M_TOT (N_B*HW)          // 65536 global rows
#define K_A 512
#define TEMP_INV (1.0f/0.3f)
#define EPS_SK 1e-12f

typedef _Float16 f16x8 __attribute__((ext_vector_type(8)));
typedef _Float16 f16x4 __attribute__((ext_vector_type(4)));
typedef float f32x4 __attribute__((ext_vector_type(4)));

#define GLOBAL_AS __attribute__((address_space(1)))
#define LDS_AS __attribute__((address_space(3)))
__device__ __forceinline__ void gload_lds16(const void* g, void* l){
    __builtin_amdgcn_global_load_lds((GLOBAL_AS const void*)g, (LDS_AS void*)l, 16, 0, 0);
}

// ---------------- fused: read x once -> L2 norm -> Lt[n][hw][c] fp16; init u=1,v=1,barrier=0 ----------------
__global__ __launch_bounds__(256) void k_normtrans(const float* __restrict__ x,
                                                   _Float16* __restrict__ Lt,
                                                   float* __restrict__ u,
                                                   float* __restrict__ v,
                                                   unsigned* bcnt, unsigned* bgen){
    __shared__ float tl[32][257];
    __shared__ float red[8][32];
    __shared__ float invs[32];
    int n   = blockIdx.x >> 7;           // 2048 blocks: 16 n x 128 hw-chunks of 32
    int hw0 = (blockIdx.x & 127) * 32;
    if (threadIdx.x < 32) u[blockIdx.x*32 + threadIdx.x] = 1.0f;
    if (blockIdx.x < 2)   v[blockIdx.x*256 + threadIdx.x] = 1.0f;
    if (blockIdx.x == 0 && threadIdx.x == 0){
        __hip_atomic_store(bcnt, 0u, __ATOMIC_RELAXED, __HIP_MEMORY_SCOPE_AGENT);
        __hip_atomic_store(bgen, 0u, __ATOMIC_RELAXED, __HIP_MEMORY_SCOPE_AGENT);
    }
    int tx4 = threadIdx.x & 7;           // hw quad
    int cy  = threadIdx.x >> 3;          // 0..31
    const float* px = x + ((size_t)(n*C_DIM + cy))*HW + hw0 + tx4*4;
    #pragma unroll
    for (int r = 0; r < 8; ++r){
        float4 xv = *(const float4*)(px + (size_t)(r*32)*HW);
        int c = cy + r*32;
        tl[tx4*4+0][c] = xv.x;
        tl[tx4*4+1][c] = xv.y;
        tl[tx4*4+2][c] = xv.z;
        tl[tx4*4+3][c] = xv.w;
    }
    __syncthreads();
    int tx = threadIdx.x & 31, ty = threadIdx.x >> 5;   // ty 0..7
    float ss = 0.f;
    #pragma unroll
    for (int cc = 0; cc < 32; ++cc){
        float tv = tl[tx][cc*8 + ty];
        ss += tv*tv;
    }
    red[ty][tx] = ss;
    __syncthreads();
    if (ty == 0){
        float s = red[0][tx]+red[1][tx]+red[2][tx]+red[3][tx]
                + red[4][tx]+red[5][tx]+red[6][tx]+red[7][tx];
        invs[tx] = 1.0f / fmaxf(sqrtf(s), 1e-12f);
    }
    __syncthreads();
    #pragma unroll
    for (int r = 0; r < 4; ++r){
        int hwl = ty + r*8;
        float inv = invs[hwl];
        f16x8 h;
        #pragma unroll
        for (int e = 0; e < 8; ++e) h[e] = (_Float16)(tl[hwl][tx*8 + e] * inv);
        *(f16x8*)&Lt[((size_t)(n*HW + hw0 + hwl))*C_DIM + tx*8] = h;
    }
}

// ---------------- gather anchors from Lt (coalesced): sxT[n][j][c] fp16 ----------------
__global__ __launch_bounds__(256) void k_gather(const _Float16* __restrict__ Lt,
                                                const int* __restrict__ sidx,
                                                _Float16* __restrict__ sxT){
    int n  = blockIdx.y;
    int jj = blockIdx.x*8 + (threadIdx.x >> 5);
    int c8 = (threadIdx.x & 31) * 8;
    int p  = sidx[jj];
    *(f16x8*)&sxT[((size_t)(n*K_A + jj))*C_DIM + c8] =
        *(const f16x8*)&Lt[((size_t)(n*HW + p))*C_DIM + c8];
}

// ======== GEMM1 + first Sinkhorn column partials ========
__global__ __launch_bounds__(256) void k_gemm1(const _Float16* __restrict__ Lt,
                                               const _Float16* __restrict__ sxT,
                                               _Float16* __restrict__ A0,
                                               float* __restrict__ part){
    __shared__ _Float16 As[3*128*32];
    __shared__ _Float16 Bs[3*128*32];
    __shared__ float colred[4][128];
    const int swz = (blockIdx.x & 7)*256 + (blockIdx.x >> 3);
    const int jb = swz & 3, mb = (swz >> 2) & 31, nb = swz >> 7;
    const int mbase = mb * 128;
    const int jbase = jb * 128;
    const int t = threadIdx.x;
    const int lane = t & 63, w = t >> 6;
    const int wm = (w >> 1)*64, wn = (w & 1)*64;
    const int l15 = lane & 15, lq = lane >> 4;

    f32x4 acc[4][4] = {};
    const _Float16* pa = Lt  + ((size_t)(nb*HW  + mbase))*C_DIM;
    const _Float16* pb = sxT + ((size_t)(nb*K_A + jbase))*C_DIM;

    const int r0 = t >> 2, ch = t & 3;
    const int r1 = r0 + 64;
    const int cs0 = (ch ^ ((r0 >> 1) & 3)) << 3;
    const int cs1 = (ch ^ ((r1 >> 1) & 3)) << 3;

#define STAGE1(buf, kt) { int k0 = (kt)*32; \
    gload_lds16(pa + (size_t)r0*C_DIM + k0 + cs0, &As[(buf)*4096 + t*8]); \
    gload_lds16(pa + (size_t)r1*C_DIM + k0 + cs1, &As[(buf)*4096 + (256+t)*8]); \
    gload_lds16(pb + (size_t)r0*C_DIM + k0 + cs0, &Bs[(buf)*4096 + t*8]); \
    gload_lds16(pb + (size_t)r1*C_DIM + k0 + cs1, &Bs[(buf)*4096 + (256+t)*8]); }

    STAGE1(0, 0); STAGE1(1, 1); STAGE1(2, 2);
    #pragma unroll
    for (int kt = 0; kt < 8; ++kt){
        if (kt < 6)      asm volatile("s_waitcnt vmcnt(8)" ::: "memory");
        else if (kt < 7) asm volatile("s_waitcnt vmcnt(4)" ::: "memory");
        else             asm volatile("s_waitcnt vmcnt(0)" ::: "memory");
        __builtin_amdgcn_s_barrier();
        __builtin_amdgcn_sched_barrier(0);
        const int cur = kt % 3;
        f16x8 af[4], bf[4];
        #pragma unroll
        for (int mi = 0; mi < 4; ++mi){
            int r = wm + mi*16 + l15;
            af[mi] = *(const f16x8*)&As[cur*4096 + r*32 + ((lq ^ ((r>>1)&3)) << 3)];
        }
        #pragma unroll
        for (int ni = 0; ni < 4; ++ni){
            int r = wn + ni*16 + l15;
            bf[ni] = *(const f16x8*)&Bs[cur*4096 + r*32 + ((lq ^ ((r>>1)&3)) << 3)];
        }
        #pragma unroll
        for (int mi = 0; mi < 4; ++mi)
            #pragma unroll
            for (int ni = 0; ni < 4; ++ni)
                acc[mi][ni] = __builtin_amdgcn_mfma_f32_16x16x32_f16(af[mi], bf[ni], acc[mi][ni], 0, 0, 0);
        __builtin_amdgcn_s_barrier();
        __builtin_amdgcn_sched_barrier(0);
        if (kt < 5) STAGE1((kt+3)%3, kt+3);
    }
    float csum[4] = {0.f, 0.f, 0.f, 0.f};
    #pragma unroll
    for (int mi = 0; mi < 4; ++mi)
        #pragma unroll
        for (int ni = 0; ni < 4; ++ni)
            #pragma unroll
            for (int r = 0; r < 4; ++r){
                int hw = mbase + wm + mi*16 + lq*4 + r;
                int j  = jbase + wn + ni*16 + l15;
                float e = __expf(acc[mi][ni][r] * TEMP_INV);
                A0[((size_t)(nb*HW + hw))*K_A + j] = (_Float16)e;
                csum[ni] += e;
            }
    #pragma unroll
    for (int ni = 0; ni < 4; ++ni){
        float cv = csum[ni];
        cv += __shfl_xor(cv, 16);
        cv += __shfl_xor(cv, 32);
        if (lane < 16) colred[w][wn + ni*16 + l15] = cv;
    }
    __syncthreads();
    if (t < 128){
        int jj = t;
        float s = (jj < 64) ? (colred[0][jj] + colred[2][jj])
                            : (colred[1][jj] + colred[3][jj]);
        part[((size_t)(nb*32 + mb))*K_A + jbase + jj] = s;
    }
}

// v[j] <- 128 * v[j] / max(v[j]*S_j, EPS)  (fallback path)
__global__ __launch_bounds__(64) void k_colfinish(const float* __restrict__ part,
                                                  float* __restrict__ v, int nchunks){
    int j = blockIdx.x;
    int lane = threadIdx.x;
    float s = 0.f;
    for (int r = lane; r < nchunks; r += 64) s += part[(size_t)r*K_A + j];
    #pragma unroll
    for (int off = 32; off; off >>= 1) s += __shfl_xor(s, off);
    if (lane == 0){
        float vo = v[j];
        v[j] = 128.0f * vo / fmaxf(vo * s, EPS_SK);
    }
}

// ---------------- FUSED row+col pass (fallback path) ----------------
__global__ __launch_bounds__(256) void k_fused(const _Float16* __restrict__ A0,
                                               const float* __restrict__ v,
                                               float* __restrict__ u,
                                               float* __restrict__ part){
    __shared__ float red[4][512];
    int b = blockIdx.x;
    int tg = threadIdx.x >> 6, lane = threadIdx.x & 63;
    float vr[8];
    const float* pv = v + (lane << 3);
    #pragma unroll
    for (int e = 0; e < 8; ++e) vr[e] = pv[e];
    float acc[8] = {};
    for (int it = 0; it < 16; ++it){
        int i = (b << 6) + (it << 2) + tg;
        f16x8 a = *(const f16x8*)&A0[(size_t)i*K_A + (lane << 3)];
        float r = 0.f;
        #pragma unroll
        for (int e = 0; e < 8; ++e) r += (float)a[e] * vr[e];
        #pragma unroll
        for (int off = 32; off; off >>= 1) r += __shfl_xor(r, off);
        float uo = u[i];
        float un = uo / fmaxf(uo * r, EPS_SK);
        if (lane == 0) u[i] = un;
        #pragma unroll
        for (int e = 0; e < 8; ++e) acc[e] += (float)a[e] * un;
    }
    #pragma unroll
    for (int e = 0; e < 8; ++e) red[tg][(lane<<3)+e] = acc[e];
    __syncthreads();
    if (tg == 0){
        #pragma unroll
        for (int e = 0; e < 8; ++e){
            int j = (lane<<3)+e;
            part[((size_t)b)*K_A + j] = red[0][j]+red[1][j]+red[2][j]+red[3][j];
        }
    }
}

// ---------------- sense-reversing grid barrier for 256 co-resident blocks ----------------
__device__ __forceinline__ void gbar256(unsigned* cnt, unsigned* gen){
    __threadfence();
    __syncthreads();
    if (threadIdx.x == 0){
        unsigned g = __hip_atomic_load(gen, __ATOMIC_RELAXED, __HIP_MEMORY_SCOPE_AGENT);
        unsigned a = __hip_atomic_fetch_add(cnt, 1u, __ATOMIC_ACQ_REL, __HIP_MEMORY_SCOPE_AGENT);
        if (a == 255u){
            __hip_atomic_store(cnt, 0u, __ATOMIC_RELAXED, __HIP_MEMORY_SCOPE_AGENT);
            __hip_atomic_store(gen, g + 1u, __ATOMIC_RELEASE, __HIP_MEMORY_SCOPE_AGENT);
        } else {
            unsigned spin = 0;
            while (__hip_atomic_load(gen, __ATOMIC_ACQUIRE, __HIP_MEMORY_SCOPE_AGENT) == g){
                __builtin_amdgcn_s_sleep(8);
                if (++spin > (1u<<22)) break;   // bounded: deadlock -> wrong result, not a hang
            }
        }
    }
    __syncthreads();
    __threadfence();
}

// col-normalize: block b owns columns 2b, 2b+1 (waves 0,1)
__device__ __forceinline__ void colfin2(const float* part, float* v, int b, int t, int nchunks){
    int tg = t >> 6, lane = t & 63;
    if (tg < 2){
        int j = b*2 + tg;
        float s = 0.f;
        for (int r = lane; r < nchunks; r += 64)
            s += __hip_atomic_load(&part[(size_t)r*K_A + j],
                                   __ATOMIC_RELAXED, __HIP_MEMORY_SCOPE_AGENT);
        #pragma unroll
        for (int off = 32; off; off >>= 1) s += __shfl_xor(s, off);
        if (lane == 0){
            float vo = __hip_atomic_load(&v[j], __ATOMIC_RELAXED, __HIP_MEMORY_SCOPE_AGENT);
            __hip_atomic_store(&v[j], 128.0f * vo / fmaxf(vo * s, EPS_SK),
                               __ATOMIC_RELAXED, __HIP_MEMORY_SCOPE_AGENT);
        }
    }
}

// ======== Persistent in-register Sinkhorn: PLAIN launch, 256 blocks x 1024 thr (1/CU) ========
// A0 read ONCE into registers (a[16] = 64 VGPR); custom grid barrier; v1..v4 + u1..u3.
__global__ __launch_bounds__(1024, 4) void k_sink(const _Float16* __restrict__ A0,
                                                  float* v, float* u, float* part,
                                                  unsigned* bcnt, unsigned* bgen){
    __shared__ float red[16][512];     // 32 KB
    const int b = blockIdx.x, t = threadIdx.x;
    const int tg = t >> 6, lane = t & 63;
    const int i0 = (b << 8) + tg;      // rows i0 + it*16, it=0..15
    f16x8 a[16];
    float ur[16];
    #pragma unroll
    for (int it = 0; it < 16; ++it){
        a[it] = *(const f16x8*)&A0[(size_t)(i0 + it*16)*K_A + (lane<<3)];
        ur[it] = 1.0f;
    }
    colfin2(part, v, b, t, 512);       // v1 from gemm1 partials (u0 = 1)
    gbar256(bcnt, bgen);
    float vr[8];
    #pragma unroll
    for (int e = 0; e < 8; ++e)
        vr[e] = __hip_atomic_load(&v[(lane<<3)+e], __ATOMIC_RELAXED, __HIP_MEMORY_SCOPE_AGENT);
    for (int t3 = 0; t3 < 3; ++t3){
        if (t3){
            gbar256(bcnt, bgen);
            #pragma unroll
            for (int e = 0; e < 8; ++e)
                vr[e] = __hip_atomic_load(&v[(lane<<3)+e], __ATOMIC_RELAXED, __HIP_MEMORY_SCOPE_AGENT);
        }
        // row update: ur <- ur / max(ur * (a . v), EPS)
        #pragma unroll
        for (int it = 0; it < 16; ++it){
            float r = 0.f;
            #pragma unroll
            for (int e = 0; e < 8; ++e) r += (float)a[it][e] * vr[e];
            #pragma unroll
            for (int off = 32; off; off >>= 1) r += __shfl_xor(r, off);
            ur[it] = ur[it] / fmaxf(ur[it] * r, EPS_SK);
        }
        // column partials over this block's 256 rows
        float acc[8] = {0.f,0.f,0.f,0.f,0.f,0.f,0.f,0.f};
        #pragma unroll
        for (int it = 0; it < 16; ++it)
            #pragma unroll
            for (int e = 0; e < 8; ++e) acc[e] += (float)a[it][e] * ur[it];
        #pragma unroll
        for (int e = 0; e < 8; ++e) red[tg][(lane<<3)+e] = acc[e];
        __syncthreads();
        if (t < K_A){
            float s = 0.f;
            #pragma unroll
            for (int g = 0; g < 16; ++g) s += red[g][t];
            __hip_atomic_store(&part[(size_t)b*K_A + t], s,
                               __ATOMIC_RELAXED, __HIP_MEMORY_SCOPE_AGENT);
        }
        gbar256(bcnt, bgen);
        colfin2(part, v, b, t, 256);   // v_{t3+2}
    }
    if (lane == 0){
        #pragma unroll
        for (int it = 0; it < 16; ++it) u[i0 + it*16] = ur[it];   // u3
    }
}

// ---------------- SXv[n][c][j] = sxT[n][j][c] * v[j]  (LDS transpose, fp16) ----------------
__global__ __launch_bounds__(256) void k_sxvT(const _Float16* __restrict__ sxT,
                                              const float* __restrict__ v,
                                              _Float16* __restrict__ SXv){
    __shared__ float tl[64][65];
    int n  = blockIdx.z;
    int j0 = blockIdx.x * 64;
    int c0 = blockIdx.y * 64;
    int tx = threadIdx.x & 63, ty = threadIdx.x >> 6;
    #pragma unroll
    for (int r = 0; r < 16; ++r){
        int jl = ty + r*4;
        tl[jl][tx] = (float)sxT[((size_t)(n*K_A + j0 + jl))*C_DIM + c0 + tx] * v[j0 + jl];
    }
    __syncthreads();
    #pragma unroll
    for (int r = 0; r < 16; ++r){
        int cl = ty + r*4;
        SXv[((size_t)(n*C_DIM + c0 + cl))*K_A + j0 + tx] = (_Float16)tl[tx][cl];
    }
}

// ======== GEMM2 + final row-normalize ========
__global__ __launch_bounds__(256) void k_gemm2(const _Float16* __restrict__ SXv,
                                               const _Float16* __restrict__ A0,
                                               const float* __restrict__ v,
                                               const float* __restrict__ u,
                                               float* __restrict__ out){
    __shared__ _Float16 As[3*128*32];
    __shared__ _Float16 Bs[3*128*32];
    __shared__ _Float16 vsh[512];
    const int swz = (blockIdx.x & 7)*128 + (blockIdx.x >> 3);
    const int mb = swz & 1, nbi = (swz >> 1) & 31, nb = swz >> 6;
    const int mbase = mb * 128;    // c
    const int nbase = nbi * 128;   // hw
    const int t = threadIdx.x;
    const int lane = t & 63, w = t >> 6;
    const int wm = (w >> 1)*64, wn = (w & 1)*64;
    const int l15 = lane & 15, lq = lane >> 4;

    vsh[t]       = (_Float16)v[t];
    vsh[t + 256] = (_Float16)v[t + 256];

    f32x4 acc[4][4] = {};
    f32x4 racc[4] = {};
    const _Float16* pa = SXv + ((size_t)(nb*C_DIM + mbase))*K_A;
    const _Float16* pb = A0  + ((size_t)(nb*HW   + nbase))*K_A;

    const int r0 = t >> 2, ch = t & 3;
    const int r1 = r0 + 64;
    const int cs0 = (ch ^ ((r0 >> 1) & 3)) << 3;
    const int cs1 = (ch ^ ((r1 >> 1) & 3)) << 3;

#define STAGE2(buf, kt) { int k0 = (kt)*32; \
    gload_lds16(pa + (size_t)r0*K_A + k0 + cs0, &As[(buf)*4096 + t*8]); \
    gload_lds16(pa + (size_t)r1*K_A + k0 + cs1, &As[(buf)*4096 + (256+t)*8]); \
    gload_lds16(pb + (size_t)r0*K_A + k0 + cs0, &Bs[(buf)*4096 + t*8]); \
    gload_lds16(pb + (size_t)r1*K_A + k0 + cs1, &Bs[(buf)*4096 + (256+t)*8]); }

    STAGE2(0, 0); STAGE2(1, 1); STAGE2(2, 2);
    #pragma unroll
    for (int kt = 0; kt < 16; ++kt){
        if (kt < 14)      asm volatile("s_waitcnt vmcnt(8)" ::: "memory");
        else if (kt < 15) asm volatile("s_waitcnt vmcnt(4)" ::: "memory");
        else              asm volatile("s_waitcnt vmcnt(0)" ::: "memory");
        __builtin_amdgcn_s_barrier();
        __builtin_amdgcn_sched_barrier(0);
        const int cur = kt % 3;
        f16x8 af[4], bf[4], vf;
        vf = *(const f16x8*)&vsh[kt*32 + lq*8];
        #pragma unroll
        for (int mi = 0; mi < 4; ++mi){
            int r = wm + mi*16 + l15;
            af[mi] = *(const f16x8*)&As[cur*4096 + r*32 + ((lq ^ ((r>>1)&3)) << 3)];
        }
        #pragma unroll
        for (int ni = 0; ni < 4; ++ni){
            int r = wn + ni*16 + l15;
            bf[ni] = *(const f16x8*)&Bs[cur*4096 + r*32 + ((lq ^ ((r>>1)&3)) << 3)];
        }
        #pragma unroll
        for (int mi = 0; mi < 4; ++mi)
            #pragma unroll
            for (int ni = 0; ni < 4; ++ni)
                acc[mi][ni] = __builtin_amdgcn_mfma_f32_16x16x32_f16(af[mi], bf[ni], acc[mi][ni], 0, 0, 0);
        #pragma unroll
        for (int ni = 0; ni < 4; ++ni)
            racc[ni] = __builtin_amdgcn_mfma_f32_16x16x32_f16(vf, bf[ni], racc[ni], 0, 0, 0);
        __builtin_amdgcn_s_barrier();
        __builtin_amdgcn_sched_barrier(0);
        if (kt < 13) STAGE2((kt+3)%3, kt+3);
    }
    float un[4];
    #pragma unroll
    for (int ni = 0; ni < 4; ++ni){
        float rv = racc[ni][0];
        float uo = u[nb*HW + nbase + wn + ni*16 + l15];
        un[ni] = uo / fmaxf(uo * rv, EPS_SK);
    }
    #pragma unroll
    for (int mi = 0; mi < 4; ++mi)
        #pragma unroll
        for (int ni = 0; ni < 4; ++ni)
            #pragma unroll
            for (int r = 0; r < 4; ++r){
                int c  = mbase + wm + mi*16 + lq*4 + r;
                int hw = nbase + wn + ni*16 + l15;
                out[((size_t)(nb*C_DIM + c))*HW + hw] = acc[mi][ni][r] * un[ni];
            }
}

extern "C" void kernel_launch(void* const* d_in, const int* in_sizes, int n_in,
                              void* d_out, int out_size, void* d_ws, size_t ws_size,
                              hipStream_t stream){
    const float* x  = (const float*)d_in[0];
    const int* sidx = (const int*)d_in[1];
    float* out = (float*)d_out;

    char* ws = (char*)d_ws;
    _Float16* Lt  = (_Float16*)ws;  ws += (size_t)N_B*HW*C_DIM*2;      // 32 MiB
    _Float16* A0  = (_Float16*)ws;  ws += (size_t)M_TOT*K_A*2;         // 64 MiB
    _Float16* sxT = (_Float16*)ws;  ws += (size_t)N_B*K_A*C_DIM*2;     // 4 MiB
    _Float16* SXv = (_Float16*)ws;  ws += (size_t)N_B*C_DIM*K_A*2;     // 4 MiB
    float*    u   = (float*)ws;     ws += (size_t)M_TOT*4;
    float*    v   = (float*)ws;     ws += (size_t)K_A*4;
    float*    part= (float*)ws;     ws += (size_t)1024*K_A*4;          // 2 MiB
    unsigned* bcnt= (unsigned*)ws;  ws += 256;
    unsigned* bgen= (unsigned*)ws;  ws += 256;

    k_normtrans<<<2048, 256, 0, stream>>>(x, Lt, u, v, bcnt, bgen);
    k_gather   <<<dim3(64,16), 256, 0, stream>>>(Lt, sidx, sxT);
    k_gemm1    <<<2048, 256, 0, stream>>>(Lt, sxT, A0, part);

    // Sinkhorn middle: persistent register-resident path (PLAIN launch, graph-capturable)
    // only if the compiled kernel has no scratch spill and fits 1 block/CU; else fallback.
    hipFuncAttributes attr{};
    bool ok = (hipFuncGetAttributes(&attr, (const void*)k_sink) == hipSuccess)
              && attr.localSizeBytes == 0 && attr.numRegs <= 128
              && attr.maxThreadsPerBlock >= 1024;
    if (ok){
        k_sink<<<256, 1024, 0, stream>>>(A0, v, u, part, bcnt, bgen);
    } else {
        k_colfinish<<<512, 64, 0, stream>>>(part, v, 512);
        for (int it = 0; it < 3; ++it){
            k_fused    <<<1024, 256, 0, stream>>>(A0, v, u, part);
            k_colfinish<<<512, 64, 0, stream>>>(part, v, 1024);
        }
    }

    k_sxvT <<<dim3(8,4,16), 256, 0, stream>>>(sxT, v, SXv);
    k_gemm2<<<1024, 256, 0, stream>>>(SXv, A0, v, u, out);
}